// Round 1
// baseline (2332.180 us; speedup 1.0000x reference)
//
#include <hip/hip_runtime.h>

#define BD 32768
#define DD 2048
#define LN_EPS 1e-5f

typedef unsigned short u16;
typedef unsigned int u32;
typedef __bf16 bf16x8 __attribute__((ext_vector_type(8)));
typedef float floatx4 __attribute__((ext_vector_type(4)));

__device__ inline u16 f2bf(float f) {
    u32 u = __builtin_bit_cast(u32, f);
    u32 r = (u + 0x7fffu + ((u >> 16) & 1u)) >> 16;
    return (u16)r;
}
__device__ inline float bf2f(u16 h) {
    return __builtin_bit_cast(float, ((u32)h) << 16);
}

__device__ inline void lds16(const void* g, void* l) {
    __builtin_amdgcn_global_load_lds(
        (const __attribute__((address_space(1))) u32*)g,
        (__attribute__((address_space(3))) u32*)l, 16, 0, 0);
}

// fp32 -> (hi, lo) bf16 split, 4 elements/thread
__global__ __launch_bounds__(256) void split_f32(const float* __restrict__ in,
                                                 u16* __restrict__ hi,
                                                 u16* __restrict__ lo, int n4) {
    int i = blockIdx.x * 256 + threadIdx.x;
    if (i >= n4) return;
    float4 f = ((const float4*)in)[i];
    u16 h0 = f2bf(f.x), h1 = f2bf(f.y), h2 = f2bf(f.z), h3 = f2bf(f.w);
    u16 l0 = f2bf(f.x - bf2f(h0)), l1 = f2bf(f.y - bf2f(h1));
    u16 l2 = f2bf(f.z - bf2f(h2)), l3 = f2bf(f.w - bf2f(h3));
    ((ushort4*)hi)[i] = make_ushort4(h0, h1, h2, h3);
    ((ushort4*)lo)[i] = make_ushort4(l0, l1, l2, l3);
}

// C[m][n] = sum_k A[m][k]*B[n][k]  (A: M x K bf16, B: N x K bf16, C: M x N fp32)
// SPLIT=1: A,B given as hi+lo pairs; compute hi*hi + hi*lo + lo*hi (fp32-ish precision).
template <int SPLIT>
__global__ __launch_bounds__(256) void gemm_bt(const u16* __restrict__ Ahi,
                                               const u16* __restrict__ Alo,
                                               const u16* __restrict__ Bhi,
                                               const u16* __restrict__ Blo,
                                               float* __restrict__ C,
                                               int M, int N, int K) {
    // LDS tiles: 128 rows x 32 k, row-major. hi tiles at 0/4096, lo at 8192/12288 (u16 units)
    __shared__ alignas(16) u16 smem[(SPLIT ? 4 : 2) * 4096];
    const int tid = threadIdx.x;
    const size_t bm = (size_t)blockIdx.y * 128;
    const size_t bn = (size_t)blockIdx.x * 128;
    const int lane = tid & 63;
    const int wave = tid >> 6;
    const int wm = (wave >> 1) * 64, wn = (wave & 1) * 64;
    const int m16 = lane & 15, q = lane >> 4;

    floatx4 acc[4][4] = {};

    const u16* Ah = Ahi + bm * K;
    const u16* Bh = Bhi + bn * K;
    const u16* Al = SPLIT ? (Alo + bm * K) : nullptr;
    const u16* Bl = SPLIT ? (Blo + bn * K) : nullptr;

    for (int k0 = 0; k0 < K; k0 += 32) {
#pragma unroll
        for (int s = 0; s < 2; ++s) {
            int e = s * 256 + tid;
            int row = e >> 2;
            int kq = (e & 3) * 8;
            size_t goff = (size_t)row * K + (size_t)k0 + kq;
            lds16(Ah + goff, &smem[e * 8]);
            lds16(Bh + goff, &smem[4096 + e * 8]);
            if (SPLIT) {
                lds16(Al + goff, &smem[8192 + e * 8]);
                lds16(Bl + goff, &smem[12288 + e * 8]);
            }
        }
        __syncthreads();

        bf16x8 ah[4], bh[4], al[4], bl[4];
#pragma unroll
        for (int i = 0; i < 4; ++i) {
            ah[i] = *(const bf16x8*)&smem[(wm + i * 16 + m16) * 32 + q * 8];
            bh[i] = *(const bf16x8*)&smem[4096 + (wn + i * 16 + m16) * 32 + q * 8];
            if (SPLIT) {
                al[i] = *(const bf16x8*)&smem[8192 + (wm + i * 16 + m16) * 32 + q * 8];
                bl[i] = *(const bf16x8*)&smem[12288 + (wn + i * 16 + m16) * 32 + q * 8];
            }
        }
#pragma unroll
        for (int i = 0; i < 4; ++i) {
#pragma unroll
            for (int j = 0; j < 4; ++j) {
                acc[i][j] = __builtin_amdgcn_mfma_f32_16x16x32_bf16(ah[i], bh[j], acc[i][j], 0, 0, 0);
                if (SPLIT) {
                    acc[i][j] = __builtin_amdgcn_mfma_f32_16x16x32_bf16(ah[i], bl[j], acc[i][j], 0, 0, 0);
                    acc[i][j] = __builtin_amdgcn_mfma_f32_16x16x32_bf16(al[i], bh[j], acc[i][j], 0, 0, 0);
                }
            }
        }
        __syncthreads();
    }

    // C/D layout (m89-verified): col = lane&15, row = (lane>>4)*4 + reg
#pragma unroll
    for (int i = 0; i < 4; ++i) {
#pragma unroll
        for (int r = 0; r < 4; ++r) {
            size_t grow = bm + wm + i * 16 + q * 4 + r;
            float* crow = C + grow * N + bn + wn + m16;
#pragma unroll
            for (int j = 0; j < 4; ++j) crow[j * 16] = acc[i][j][r];
        }
    }
}

// Per-row: h += b1; LayerNorm; ReLU; logits = W2 @ h + b2.
// mode 0: write route (argmax). mode 1: write logits pair. mode 2: select(route, fake, this)->out.
__global__ __launch_bounds__(256) void ln_head(const float* __restrict__ h,
                                               const float* __restrict__ b1,
                                               const float* __restrict__ g,
                                               const float* __restrict__ be,
                                               const float* __restrict__ W2,
                                               const float* __restrict__ b2,
                                               int mode,
                                               const int* __restrict__ route_in,
                                               const float* __restrict__ fake_in,
                                               int* __restrict__ route_out,
                                               float* __restrict__ out) {
    const int wave = threadIdx.x >> 6, lane = threadIdx.x & 63;
    const size_t row = (size_t)blockIdx.x * 4 + wave;
    const float* hr = h + row * DD;

    float v[32];
    float sum = 0.f, sumsq = 0.f;
#pragma unroll
    for (int i = 0; i < 8; ++i) {
        int col = i * 256 + lane * 4;
        float4 t = *(const float4*)(hr + col);
        float4 bb = *(const float4*)(b1 + col);
        t.x += bb.x; t.y += bb.y; t.z += bb.z; t.w += bb.w;
        v[i * 4 + 0] = t.x; v[i * 4 + 1] = t.y; v[i * 4 + 2] = t.z; v[i * 4 + 3] = t.w;
        sum += t.x + t.y + t.z + t.w;
        sumsq += t.x * t.x + t.y * t.y + t.z * t.z + t.w * t.w;
    }
#pragma unroll
    for (int off = 32; off > 0; off >>= 1) {
        sum += __shfl_xor(sum, off);
        sumsq += __shfl_xor(sumsq, off);
    }
    const float mu = sum * (1.f / 2048.f);
    const float var = sumsq * (1.f / 2048.f) - mu * mu;
    const float rstd = rsqrtf(var + LN_EPS);

    float l0 = 0.f, l1 = 0.f;
#pragma unroll
    for (int i = 0; i < 8; ++i) {
        int col = i * 256 + lane * 4;
        float4 gg = *(const float4*)(g + col);
        float4 bbe = *(const float4*)(be + col);
        float4 w0 = *(const float4*)(W2 + col);
        float4 w1 = *(const float4*)(W2 + DD + col);
        float hn;
        hn = fmaxf((v[i * 4 + 0] - mu) * rstd * gg.x + bbe.x, 0.f); l0 += hn * w0.x; l1 += hn * w1.x;
        hn = fmaxf((v[i * 4 + 1] - mu) * rstd * gg.y + bbe.y, 0.f); l0 += hn * w0.y; l1 += hn * w1.y;
        hn = fmaxf((v[i * 4 + 2] - mu) * rstd * gg.z + bbe.z, 0.f); l0 += hn * w0.z; l1 += hn * w1.z;
        hn = fmaxf((v[i * 4 + 3] - mu) * rstd * gg.w + bbe.w, 0.f); l0 += hn * w0.w; l1 += hn * w1.w;
    }
#pragma unroll
    for (int off = 32; off > 0; off >>= 1) {
        l0 += __shfl_xor(l0, off);
        l1 += __shfl_xor(l1, off);
    }
    if (lane == 0) {
        l0 += b2[0]; l1 += b2[1];
        if (mode == 0) {
            route_out[row] = (l0 >= l1) ? 0 : 1;   // argmax ties -> index 0
        } else if (mode == 1) {
            out[row * 2 + 0] = l0; out[row * 2 + 1] = l1;
        } else {
            if (route_in[row] == 0) {
                out[row * 2 + 0] = fake_in[row * 2 + 0];
                out[row * 2 + 1] = fake_in[row * 2 + 1];
            } else {
                out[row * 2 + 0] = l0; out[row * 2 + 1] = l1;
            }
        }
    }
}

extern "C" void kernel_launch(void* const* d_in, const int* in_sizes, int n_in,
                              void* d_out, int out_size, void* d_ws, size_t ws_size,
                              hipStream_t stream) {
    const float* x = (const float*)d_in[0];
    const float* W1[3] = {(const float*)d_in[1], (const float*)d_in[7], (const float*)d_in[13]};
    const float* b1[3] = {(const float*)d_in[2], (const float*)d_in[8], (const float*)d_in[14]};
    const float* lg[3] = {(const float*)d_in[3], (const float*)d_in[9], (const float*)d_in[15]};
    const float* lb[3] = {(const float*)d_in[4], (const float*)d_in[10], (const float*)d_in[16]};
    const float* W2[3] = {(const float*)d_in[5], (const float*)d_in[11], (const float*)d_in[17]};
    const float* b2[3] = {(const float*)d_in[6], (const float*)d_in[12], (const float*)d_in[18]};

    char* ws = (char*)d_ws;
    size_t off = 0;
    u16* x_hi = (u16*)(ws + off); off += (size_t)BD * DD * 2;      // 134 MB
    u16* x_lo = (u16*)(ws + off); off += (size_t)BD * DD * 2;      // 134 MB
    u16* w_hi[3];
    u16* w_lo[3];
    for (int i = 0; i < 3; ++i) { w_hi[i] = (u16*)(ws + off); off += (size_t)DD * DD * 2; }
    for (int i = 0; i < 3; ++i) { w_lo[i] = (u16*)(ws + off); off += (size_t)DD * DD * 2; }
    float* h = (float*)(ws + off); off += (size_t)BD * DD * 4;     // 268 MB
    int* route = (int*)(ws + off); off += (size_t)BD * 4;
    float* fakel = (float*)(ws + off); off += (size_t)BD * 2 * 4;

    // 1) precision splits
    split_f32<<<(BD * DD / 4) / 256, 256, 0, stream>>>(x, x_hi, x_lo, BD * DD / 4);
    for (int i = 0; i < 3; ++i)
        split_f32<<<(DD * DD / 4) / 256, 256, 0, stream>>>(W1[i], w_hi[i], w_lo[i], DD * DD / 4);

    dim3 grid(DD / 128, BD / 128);  // (16, 256)

    // 2) first branch: 3-chain split GEMM (route precision), then route
    gemm_bt<1><<<grid, 256, 0, stream>>>(x_hi, x_lo, w_hi[0], w_lo[0], h, BD, DD, DD);
    ln_head<<<BD / 4, 256, 0, stream>>>(h, b1[0], lg[0], lb[0], W2[0], b2[0], 0,
                                        nullptr, nullptr, route, nullptr);

    // 3) fake branch: plain bf16 GEMM, store logits
    gemm_bt<0><<<grid, 256, 0, stream>>>(x_hi, nullptr, w_hi[1], nullptr, h, BD, DD, DD);
    ln_head<<<BD / 4, 256, 0, stream>>>(h, b1[1], lg[1], lb[1], W2[1], b2[1], 1,
                                        nullptr, nullptr, nullptr, fakel);

    // 4) real branch: plain bf16 GEMM, select into output
    gemm_bt<0><<<grid, 256, 0, stream>>>(x_hi, nullptr, w_hi[2], nullptr, h, BD, DD, DD);
    ln_head<<<BD / 4, 256, 0, stream>>>(h, b1[2], lg[2], lb[2], W2[2], b2[2], 2,
                                        route, fakel, nullptr, (float*)d_out);
}

// Round 2
// 2247.611 us; speedup vs baseline: 1.0376x; 1.0376x over previous
//
#include <hip/hip_runtime.h>

#define BD 32768
#define DD 2048
#define LN_EPS 1e-5f

typedef unsigned short u16;
typedef unsigned int u32;
typedef __bf16 bf16x8 __attribute__((ext_vector_type(8)));
typedef float floatx4 __attribute__((ext_vector_type(4)));

__device__ inline u16 f2bf(float f) {
    u32 u = __builtin_bit_cast(u32, f);
    u32 r = (u + 0x7fffu + ((u >> 16) & 1u)) >> 16;
    return (u16)r;
}
__device__ inline float bf2f(u16 h) {
    return __builtin_bit_cast(float, ((u32)h) << 16);
}

__device__ inline void lds16(const void* g, void* l) {
    __builtin_amdgcn_global_load_lds(
        (const __attribute__((address_space(1))) u32*)g,
        (__attribute__((address_space(3))) u32*)l, 16, 0, 0);
}

// fp32 -> (hi, lo) bf16 split, 4 elements/thread
__global__ __launch_bounds__(256) void split_f32(const float* __restrict__ in,
                                                 u16* __restrict__ hi,
                                                 u16* __restrict__ lo, int n4) {
    int i = blockIdx.x * 256 + threadIdx.x;
    if (i >= n4) return;
    float4 f = ((const float4*)in)[i];
    u16 h0 = f2bf(f.x), h1 = f2bf(f.y), h2 = f2bf(f.z), h3 = f2bf(f.w);
    u16 l0 = f2bf(f.x - bf2f(h0)), l1 = f2bf(f.y - bf2f(h1));
    u16 l2 = f2bf(f.z - bf2f(h2)), l3 = f2bf(f.w - bf2f(h3));
    ((ushort4*)hi)[i] = make_ushort4(h0, h1, h2, h3);
    ((ushort4*)lo)[i] = make_ushort4(l0, l1, l2, l3);
}

// C[m][n] = sum_k A[m][k]*B[n][k]  (A: M x K bf16, B: N x K bf16, C: M x N fp32)
// SPLIT=1: A,B given as hi+lo pairs; compute hi*hi + hi*lo + lo*hi (fp32-ish precision).
//
// LDS tiles are 128 rows x 32 k, row-major, with the 4 k-quads (8 bf16 = 16B each)
// XOR-swizzled within each row: slot c holds global quad  c ^ ((row>>1)&3).
// This makes every 8-lane phase of the fragment ds_read_b128 hit all 8 bank
// groups (was 2 of 8 -> ~4x serialization, SQ_LDS_BANK_CONFLICT=6.7e7).
template <int SPLIT>
__global__ __launch_bounds__(256) void gemm_bt(const u16* __restrict__ Ahi,
                                               const u16* __restrict__ Alo,
                                               const u16* __restrict__ Bhi,
                                               const u16* __restrict__ Blo,
                                               float* __restrict__ C,
                                               int M, int N, int K) {
    __shared__ alignas(16) u16 smem[(SPLIT ? 4 : 2) * 4096];
    const int tid = threadIdx.x;
    const size_t bm = (size_t)blockIdx.y * 128;
    const size_t bn = (size_t)blockIdx.x * 128;
    const int lane = tid & 63;
    const int wave = tid >> 6;
    const int wm = (wave >> 1) * 64, wn = (wave & 1) * 64;
    const int m16 = lane & 15, q = lane >> 4;
    // fragment-read swizzle: quad slot for (row with low4=m16, quad q)
    const int swz = (q ^ ((m16 >> 1) & 3)) * 8;

    floatx4 acc[4][4] = {};

    const u16* Ah = Ahi + bm * K;
    const u16* Bh = Bhi + bn * K;
    const u16* Al = SPLIT ? (Alo + bm * K) : nullptr;
    const u16* Bl = SPLIT ? (Blo + bn * K) : nullptr;

    for (int k0 = 0; k0 < K; k0 += 32) {
#pragma unroll
        for (int s = 0; s < 2; ++s) {
            int e = s * 256 + tid;
            int row = e >> 2;
            int c = e & 3;
            int kq = (c ^ ((row >> 1) & 3)) * 8;   // staging-side swizzle
            size_t goff = (size_t)row * K + (size_t)k0 + kq;
            lds16(Ah + goff, &smem[e * 8]);
            lds16(Bh + goff, &smem[4096 + e * 8]);
            if (SPLIT) {
                lds16(Al + goff, &smem[8192 + e * 8]);
                lds16(Bl + goff, &smem[12288 + e * 8]);
            }
        }
        __syncthreads();

        bf16x8 ah[4], bh[4], al[4], bl[4];
#pragma unroll
        for (int i = 0; i < 4; ++i) {
            ah[i] = *(const bf16x8*)&smem[(wm + i * 16 + m16) * 32 + swz];
            bh[i] = *(const bf16x8*)&smem[4096 + (wn + i * 16 + m16) * 32 + swz];
            if (SPLIT) {
                al[i] = *(const bf16x8*)&smem[8192 + (wm + i * 16 + m16) * 32 + swz];
                bl[i] = *(const bf16x8*)&smem[12288 + (wn + i * 16 + m16) * 32 + swz];
            }
        }
#pragma unroll
        for (int i = 0; i < 4; ++i) {
#pragma unroll
            for (int j = 0; j < 4; ++j) {
                acc[i][j] = __builtin_amdgcn_mfma_f32_16x16x32_bf16(ah[i], bh[j], acc[i][j], 0, 0, 0);
                if (SPLIT) {
                    acc[i][j] = __builtin_amdgcn_mfma_f32_16x16x32_bf16(ah[i], bl[j], acc[i][j], 0, 0, 0);
                    acc[i][j] = __builtin_amdgcn_mfma_f32_16x16x32_bf16(al[i], bh[j], acc[i][j], 0, 0, 0);
                }
            }
        }
        __syncthreads();
    }

    // C/D layout (m89-verified): col = lane&15, row = (lane>>4)*4 + reg
#pragma unroll
    for (int i = 0; i < 4; ++i) {
#pragma unroll
        for (int r = 0; r < 4; ++r) {
            size_t grow = bm + wm + i * 16 + q * 4 + r;
            float* crow = C + grow * N + bn + wn + m16;
#pragma unroll
            for (int j = 0; j < 4; ++j) crow[j * 16] = acc[i][j][r];
        }
    }
}

// Per-row: h += b1; LayerNorm; ReLU; logits = W2 @ h + b2.
// mode 0: write route (argmax). mode 1: write logits pair. mode 2: select(route, fake, this)->out.
__global__ __launch_bounds__(256) void ln_head(const float* __restrict__ h,
                                               const float* __restrict__ b1,
                                               const float* __restrict__ g,
                                               const float* __restrict__ be,
                                               const float* __restrict__ W2,
                                               const float* __restrict__ b2,
                                               int mode,
                                               const int* __restrict__ route_in,
                                               const float* __restrict__ fake_in,
                                               int* __restrict__ route_out,
                                               float* __restrict__ out) {
    const int wave = threadIdx.x >> 6, lane = threadIdx.x & 63;
    const size_t row = (size_t)blockIdx.x * 4 + wave;
    const float* hr = h + row * DD;

    float v[32];
    float sum = 0.f, sumsq = 0.f;
#pragma unroll
    for (int i = 0; i < 8; ++i) {
        int col = i * 256 + lane * 4;
        float4 t = *(const float4*)(hr + col);
        float4 bb = *(const float4*)(b1 + col);
        t.x += bb.x; t.y += bb.y; t.z += bb.z; t.w += bb.w;
        v[i * 4 + 0] = t.x; v[i * 4 + 1] = t.y; v[i * 4 + 2] = t.z; v[i * 4 + 3] = t.w;
        sum += t.x + t.y + t.z + t.w;
        sumsq += t.x * t.x + t.y * t.y + t.z * t.z + t.w * t.w;
    }
#pragma unroll
    for (int off = 32; off > 0; off >>= 1) {
        sum += __shfl_xor(sum, off);
        sumsq += __shfl_xor(sumsq, off);
    }
    const float mu = sum * (1.f / 2048.f);
    const float var = sumsq * (1.f / 2048.f) - mu * mu;
    const float rstd = rsqrtf(var + LN_EPS);

    float l0 = 0.f, l1 = 0.f;
#pragma unroll
    for (int i = 0; i < 8; ++i) {
        int col = i * 256 + lane * 4;
        float4 gg = *(const float4*)(g + col);
        float4 bbe = *(const float4*)(be + col);
        float4 w0 = *(const float4*)(W2 + col);
        float4 w1 = *(const float4*)(W2 + DD + col);
        float hn;
        hn = fmaxf((v[i * 4 + 0] - mu) * rstd * gg.x + bbe.x, 0.f); l0 += hn * w0.x; l1 += hn * w1.x;
        hn = fmaxf((v[i * 4 + 1] - mu) * rstd * gg.y + bbe.y, 0.f); l0 += hn * w0.y; l1 += hn * w1.y;
        hn = fmaxf((v[i * 4 + 2] - mu) * rstd * gg.z + bbe.z, 0.f); l0 += hn * w0.z; l1 += hn * w1.z;
        hn = fmaxf((v[i * 4 + 3] - mu) * rstd * gg.w + bbe.w, 0.f); l0 += hn * w0.w; l1 += hn * w1.w;
    }
#pragma unroll
    for (int off = 32; off > 0; off >>= 1) {
        l0 += __shfl_xor(l0, off);
        l1 += __shfl_xor(l1, off);
    }
    if (lane == 0) {
        l0 += b2[0]; l1 += b2[1];
        if (mode == 0) {
            route_out[row] = (l0 >= l1) ? 0 : 1;   // argmax ties -> index 0
        } else if (mode == 1) {
            out[row * 2 + 0] = l0; out[row * 2 + 1] = l1;
        } else {
            if (route_in[row] == 0) {
                out[row * 2 + 0] = fake_in[row * 2 + 0];
                out[row * 2 + 1] = fake_in[row * 2 + 1];
            } else {
                out[row * 2 + 0] = l0; out[row * 2 + 1] = l1;
            }
        }
    }
}

extern "C" void kernel_launch(void* const* d_in, const int* in_sizes, int n_in,
                              void* d_out, int out_size, void* d_ws, size_t ws_size,
                              hipStream_t stream) {
    const float* x = (const float*)d_in[0];
    const float* W1[3] = {(const float*)d_in[1], (const float*)d_in[7], (const float*)d_in[13]};
    const float* b1[3] = {(const float*)d_in[2], (const float*)d_in[8], (const float*)d_in[14]};
    const float* lg[3] = {(const float*)d_in[3], (const float*)d_in[9], (const float*)d_in[15]};
    const float* lb[3] = {(const float*)d_in[4], (const float*)d_in[10], (const float*)d_in[16]};
    const float* W2[3] = {(const float*)d_in[5], (const float*)d_in[11], (const float*)d_in[17]};
    const float* b2[3] = {(const float*)d_in[6], (const float*)d_in[12], (const float*)d_in[18]};

    char* ws = (char*)d_ws;
    size_t off = 0;
    u16* x_hi = (u16*)(ws + off); off += (size_t)BD * DD * 2;      // 134 MB
    u16* x_lo = (u16*)(ws + off); off += (size_t)BD * DD * 2;      // 134 MB
    u16* w_hi[3];
    u16* w_lo[3];
    for (int i = 0; i < 3; ++i) { w_hi[i] = (u16*)(ws + off); off += (size_t)DD * DD * 2; }
    for (int i = 0; i < 3; ++i) { w_lo[i] = (u16*)(ws + off); off += (size_t)DD * DD * 2; }
    float* h = (float*)(ws + off); off += (size_t)BD * DD * 4;     // 268 MB
    int* route = (int*)(ws + off); off += (size_t)BD * 4;
    float* fakel = (float*)(ws + off); off += (size_t)BD * 2 * 4;

    // 1) precision splits
    split_f32<<<(BD * DD / 4) / 256, 256, 0, stream>>>(x, x_hi, x_lo, BD * DD / 4);
    for (int i = 0; i < 3; ++i)
        split_f32<<<(DD * DD / 4) / 256, 256, 0, stream>>>(W1[i], w_hi[i], w_lo[i], DD * DD / 4);

    dim3 grid(DD / 128, BD / 128);  // (16, 256)

    // 2) first branch: 3-chain split GEMM (route precision), then route
    gemm_bt<1><<<grid, 256, 0, stream>>>(x_hi, x_lo, w_hi[0], w_lo[0], h, BD, DD, DD);
    ln_head<<<BD / 4, 256, 0, stream>>>(h, b1[0], lg[0], lb[0], W2[0], b2[0], 0,
                                        nullptr, nullptr, route, nullptr);

    // 3) fake branch: plain bf16 GEMM, store logits
    gemm_bt<0><<<grid, 256, 0, stream>>>(x_hi, nullptr, w_hi[1], nullptr, h, BD, DD, DD);
    ln_head<<<BD / 4, 256, 0, stream>>>(h, b1[1], lg[1], lb[1], W2[1], b2[1], 1,
                                        nullptr, nullptr, nullptr, fakel);

    // 4) real branch: plain bf16 GEMM, select into output
    gemm_bt<0><<<grid, 256, 0, stream>>>(x_hi, nullptr, w_hi[2], nullptr, h, BD, DD, DD);
    ln_head<<<BD / 4, 256, 0, stream>>>(h, b1[2], lg[2], lb[2], W2[2], b2[2], 2,
                                        route, fakel, nullptr, (float*)d_out);
}

// Round 3
// 2015.714 us; speedup vs baseline: 1.1570x; 1.1150x over previous
//
#include <hip/hip_runtime.h>

#define BD 32768
#define DD 2048
#define LN_EPS 1e-5f
#define MARGIN 0.02f
#define UCAP 8192          // max rows re-checked at split precision (expected ~1.6k)
#define IDX_CAP 33024      // 32768 + 2*128 padding

typedef unsigned short u16;
typedef unsigned int u32;
typedef __bf16 bf16x8 __attribute__((ext_vector_type(8)));
typedef float floatx4 __attribute__((ext_vector_type(4)));

// ctrl layout: [0]=nf (count route==0), [1]=u_cnt, [2]=nf snapshot, [3]=nf_pad,
//              [4]=cursor_fake, [5]=cursor_real
__device__ inline u16 f2bf(float f) {
    u32 u = __builtin_bit_cast(u32, f);
    u32 r = (u + 0x7fffu + ((u >> 16) & 1u)) >> 16;
    return (u16)r;
}
__device__ inline float bf2f(u16 h) {
    return __builtin_bit_cast(float, ((u32)h) << 16);
}

__device__ inline void lds16(const void* g, void* l) {
    __builtin_amdgcn_global_load_lds(
        (const __attribute__((address_space(1))) u32*)g,
        (__attribute__((address_space(3))) u32*)l, 16, 0, 0);
}

__global__ __launch_bounds__(256) void zero_misc(int* idx_all, int* u_idx, int* ctrl) {
    int t = blockIdx.x * 256 + threadIdx.x;
    if (t < IDX_CAP) idx_all[t] = 0;
    if (t < UCAP) u_idx[t] = 0;
    if (t < 8) ctrl[t] = 0;
}

// fp32 -> (hi, lo) bf16 split, 4 elements/thread
__global__ __launch_bounds__(256) void split_f32(const float* __restrict__ in,
                                                 u16* __restrict__ hi,
                                                 u16* __restrict__ lo, int n4) {
    int i = blockIdx.x * 256 + threadIdx.x;
    if (i >= n4) return;
    float4 f = ((const float4*)in)[i];
    u16 h0 = f2bf(f.x), h1 = f2bf(f.y), h2 = f2bf(f.z), h3 = f2bf(f.w);
    u16 l0 = f2bf(f.x - bf2f(h0)), l1 = f2bf(f.y - bf2f(h1));
    u16 l2 = f2bf(f.z - bf2f(h2)), l3 = f2bf(f.w - bf2f(h3));
    ((ushort4*)hi)[i] = make_ushort4(h0, h1, h2, h3);
    ((ushort4*)lo)[i] = make_ushort4(l0, l1, l2, l3);
}

// C[m][n] = sum_k A[m][k]*B[n][k], K=N=2048. 128x128 tile, BK=32, swizzled LDS.
// SPLIT: 3-chain hi*hi+hi*lo+lo*hi (fp32-ish precision).
// IDX:   A rows gathered via ridx; row-blocks beyond device-side limit exit.
// DUAL:  B selected per row-block: fake segment [0,nf_pad), real after.
template <int SPLIT, int IDX, int DUAL>
__global__ __launch_bounds__(256) void gemm_bt(const u16* __restrict__ Ahi,
                                               const u16* __restrict__ Alo,
                                               const u16* __restrict__ Bhi,
                                               const u16* __restrict__ Blo,
                                               const u16* __restrict__ Bhi2,
                                               float* __restrict__ C,
                                               const int* __restrict__ ridx,
                                               const int* __restrict__ ctrl) {
    const int tid = threadIdx.x;
    const size_t bm = (size_t)blockIdx.y * 128;
    const size_t bn = (size_t)blockIdx.x * 128;

    if (DUAL) {
        int nf_pad = ctrl[3];
        int limit = nf_pad + (BD - ctrl[2]);       // nf_pad + nr
        if ((int)bm >= limit) return;
        if ((int)bm >= nf_pad) Bhi = Bhi2;
    } else if (IDX) {
        int u = ctrl[1]; if (u > UCAP) u = UCAP;
        if ((int)bm >= u) return;
    }

    __shared__ alignas(16) u16 smem[(SPLIT ? 4 : 2) * 4096];
    const int lane = tid & 63;
    const int wave = tid >> 6;
    const int wm = (wave >> 1) * 64, wn = (wave & 1) * 64;
    const int m16 = lane & 15, q = lane >> 4;
    const int swz = (q ^ ((m16 >> 1) & 3)) * 8;    // fragment-read swizzle slot

    // staging geometry (hoisted): per s-half, this thread loads one 16B quad
    int aRow[2], kq[2];
    size_t bOff[2];
#pragma unroll
    for (int s = 0; s < 2; ++s) {
        int e = s * 256 + tid;
        int row = e >> 2;
        int c = e & 3;
        kq[s] = (c ^ ((row >> 1) & 3)) * 8;        // staging-side swizzle
        aRow[s] = IDX ? ridx[bm + row] : (int)(bm + row);
        bOff[s] = (size_t)(bn + row) * DD;
    }

    floatx4 acc[4][4] = {};

    for (int k0 = 0; k0 < DD; k0 += 32) {
#pragma unroll
        for (int s = 0; s < 2; ++s) {
            int e = s * 256 + tid;
            size_t aoff = (size_t)aRow[s] * DD + k0 + kq[s];
            size_t boff = bOff[s] + k0 + kq[s];
            lds16(Ahi + aoff, &smem[e * 8]);
            lds16(Bhi + boff, &smem[4096 + e * 8]);
            if (SPLIT) {
                lds16(Alo + aoff, &smem[8192 + e * 8]);
                lds16(Blo + boff, &smem[12288 + e * 8]);
            }
        }
        __syncthreads();

        bf16x8 ah[4], bh[4], al[4], bl[4];
#pragma unroll
        for (int i = 0; i < 4; ++i) {
            ah[i] = *(const bf16x8*)&smem[(wm + i * 16 + m16) * 32 + swz];
            bh[i] = *(const bf16x8*)&smem[4096 + (wn + i * 16 + m16) * 32 + swz];
            if (SPLIT) {
                al[i] = *(const bf16x8*)&smem[8192 + (wm + i * 16 + m16) * 32 + swz];
                bl[i] = *(const bf16x8*)&smem[12288 + (wn + i * 16 + m16) * 32 + swz];
            }
        }
#pragma unroll
        for (int i = 0; i < 4; ++i) {
#pragma unroll
            for (int j = 0; j < 4; ++j) {
                acc[i][j] = __builtin_amdgcn_mfma_f32_16x16x32_bf16(ah[i], bh[j], acc[i][j], 0, 0, 0);
                if (SPLIT) {
                    acc[i][j] = __builtin_amdgcn_mfma_f32_16x16x32_bf16(ah[i], bl[j], acc[i][j], 0, 0, 0);
                    acc[i][j] = __builtin_amdgcn_mfma_f32_16x16x32_bf16(al[i], bh[j], acc[i][j], 0, 0, 0);
                }
            }
        }
        __syncthreads();
    }

    // C/D layout (m89-verified): col = lane&15, row = (lane>>4)*4 + reg
#pragma unroll
    for (int i = 0; i < 4; ++i) {
#pragma unroll
        for (int r = 0; r < 4; ++r) {
            size_t grow = bm + wm + i * 16 + q * 4 + r;
            float* crow = C + grow * DD + bn + wn + m16;
#pragma unroll
            for (int j = 0; j < 4; ++j) crow[j * 16] = acc[i][j][r];
        }
    }
}

// h row -> (l0, l1): +b1, LayerNorm, ReLU, W2 dot + b2. All lanes end with l0,l1.
__device__ inline void ln_core(const float* __restrict__ hr,
                               const float* __restrict__ b1,
                               const float* __restrict__ g,
                               const float* __restrict__ be,
                               const float* __restrict__ W2,
                               const float* __restrict__ b2,
                               int lane, float& L0, float& L1) {
    float v[32];
    float sum = 0.f, sumsq = 0.f;
#pragma unroll
    for (int i = 0; i < 8; ++i) {
        int col = i * 256 + lane * 4;
        float4 t = *(const float4*)(hr + col);
        float4 bb = *(const float4*)(b1 + col);
        t.x += bb.x; t.y += bb.y; t.z += bb.z; t.w += bb.w;
        v[i * 4 + 0] = t.x; v[i * 4 + 1] = t.y; v[i * 4 + 2] = t.z; v[i * 4 + 3] = t.w;
        sum += t.x + t.y + t.z + t.w;
        sumsq += t.x * t.x + t.y * t.y + t.z * t.z + t.w * t.w;
    }
#pragma unroll
    for (int off = 32; off > 0; off >>= 1) {
        sum += __shfl_xor(sum, off);
        sumsq += __shfl_xor(sumsq, off);
    }
    const float mu = sum * (1.f / 2048.f);
    const float var = sumsq * (1.f / 2048.f) - mu * mu;
    const float rstd = rsqrtf(var + LN_EPS);

    float l0 = 0.f, l1 = 0.f;
#pragma unroll
    for (int i = 0; i < 8; ++i) {
        int col = i * 256 + lane * 4;
        float4 gg = *(const float4*)(g + col);
        float4 bbe = *(const float4*)(be + col);
        float4 w0 = *(const float4*)(W2 + col);
        float4 w1 = *(const float4*)(W2 + DD + col);
        float hn;
        hn = fmaxf((v[i * 4 + 0] - mu) * rstd * gg.x + bbe.x, 0.f); l0 += hn * w0.x; l1 += hn * w1.x;
        hn = fmaxf((v[i * 4 + 1] - mu) * rstd * gg.y + bbe.y, 0.f); l0 += hn * w0.y; l1 += hn * w1.y;
        hn = fmaxf((v[i * 4 + 2] - mu) * rstd * gg.z + bbe.z, 0.f); l0 += hn * w0.z; l1 += hn * w1.z;
        hn = fmaxf((v[i * 4 + 3] - mu) * rstd * gg.w + bbe.w, 0.f); l0 += hn * w0.w; l1 += hn * w1.w;
    }
#pragma unroll
    for (int off = 32; off > 0; off >>= 1) {
        l0 += __shfl_xor(l0, off);
        l1 += __shfl_xor(l1, off);
    }
    L0 = l0 + b2[0];
    L1 = l1 + b2[1];
}

// Branch-1 pass: route = argmax, count nf, flag near-tie rows for split-precision recheck.
__global__ __launch_bounds__(256) void ln_route(const float* __restrict__ h,
                                                const float* __restrict__ b1,
                                                const float* __restrict__ g,
                                                const float* __restrict__ be,
                                                const float* __restrict__ W2,
                                                const float* __restrict__ b2,
                                                int* __restrict__ route,
                                                int* __restrict__ ctrl,
                                                int* __restrict__ u_idx) {
    const int wave = threadIdx.x >> 6, lane = threadIdx.x & 63;
    const size_t row = (size_t)blockIdx.x * 4 + wave;
    float l0, l1;
    ln_core(h + row * DD, b1, g, be, W2, b2, lane, l0, l1);
    if (lane == 0) {
        int rt = (l0 >= l1) ? 0 : 1;
        route[row] = rt;
        atomicAdd(&ctrl[0], rt == 0 ? 1 : 0);
        if (fabsf(l0 - l1) < MARGIN) {
            int p = atomicAdd(&ctrl[1], 1);
            if (p < UCAP) u_idx[p] = (int)row;
        }
    }
}

// Recheck flagged rows with split-precision h (h rows [0,u_cnt) in gathered order).
__global__ __launch_bounds__(256) void ln_fixup(const float* __restrict__ h,
                                                const float* __restrict__ b1,
                                                const float* __restrict__ g,
                                                const float* __restrict__ be,
                                                const float* __restrict__ W2,
                                                const float* __restrict__ b2,
                                                int* __restrict__ route,
                                                int* __restrict__ ctrl,
                                                const int* __restrict__ u_idx) {
    const int wave = threadIdx.x >> 6, lane = threadIdx.x & 63;
    const int r = blockIdx.x * 4 + wave;
    int u = ctrl[1]; if (u > UCAP) u = UCAP;
    if (r >= u) return;
    const int orig = u_idx[r];
    float l0, l1;
    ln_core(h + (size_t)r * DD, b1, g, be, W2, b2, lane, l0, l1);
    if (lane == 0) {
        int rt = (l0 >= l1) ? 0 : 1;
        int old = route[orig];
        if (rt != old) {
            atomicAdd(&ctrl[0], rt == 0 ? 1 : -1);
            route[orig] = rt;
        }
    }
}

__global__ void init_ctrl(int* ctrl) {
    int nf = ctrl[0];
    ctrl[2] = nf;
    ctrl[3] = (nf + 127) & ~127;
    ctrl[4] = 0;
    ctrl[5] = ctrl[3];
}

// Compact rows: fake segment at [0,nf), real segment at [nf_pad, nf_pad+nr).
__global__ __launch_bounds__(256) void compact(const int* __restrict__ route,
                                               int* __restrict__ ctrl,
                                               int* __restrict__ idx_all) {
    const int row = blockIdx.x * 256 + threadIdx.x;
    const int lane = threadIdx.x & 63;
    const bool isf = (route[row] == 0);
    unsigned long long m = __ballot(isf);
    int nfw = __popcll(m);
    int baseF = 0, baseR = 0;
    if (lane == 0) {
        baseF = atomicAdd(&ctrl[4], nfw);
        baseR = atomicAdd(&ctrl[5], 64 - nfw);
    }
    baseF = __shfl(baseF, 0);
    baseR = __shfl(baseR, 0);
    unsigned long long lt = (lane == 0) ? 0ull : ((~0ull) >> (64 - lane));
    int pre = __popcll(m & lt);
    int pos = isf ? (baseF + pre) : (baseR + (lane - pre));
    idx_all[pos] = row;
}

// Final pass over combined gathered h: per-segment params, scatter to out[orig].
__global__ __launch_bounds__(256) void ln_final(const float* __restrict__ h,
                                                const float* __restrict__ b1f, const float* __restrict__ gf,
                                                const float* __restrict__ bef, const float* __restrict__ W2f,
                                                const float* __restrict__ b2f,
                                                const float* __restrict__ b1r, const float* __restrict__ gr,
                                                const float* __restrict__ ber, const float* __restrict__ W2r,
                                                const float* __restrict__ b2r,
                                                const int* __restrict__ ctrl,
                                                const int* __restrict__ idx_all,
                                                float* __restrict__ out) {
    const int wave = threadIdx.x >> 6, lane = threadIdx.x & 63;
    const int r = blockIdx.x * 4 + wave;
    const int nf = ctrl[2], nf_pad = ctrl[3];
    const int nr = BD - nf;
    bool fake;
    if (r < nf) fake = true;
    else if (r >= nf_pad && r < nf_pad + nr) fake = false;
    else return;
    const int orig = idx_all[r];
    float l0, l1;
    ln_core(h + (size_t)r * DD,
            fake ? b1f : b1r, fake ? gf : gr, fake ? bef : ber,
            fake ? W2f : W2r, fake ? b2f : b2r, lane, l0, l1);
    if (lane == 0) {
        out[(size_t)orig * 2 + 0] = l0;
        out[(size_t)orig * 2 + 1] = l1;
    }
}

extern "C" void kernel_launch(void* const* d_in, const int* in_sizes, int n_in,
                              void* d_out, int out_size, void* d_ws, size_t ws_size,
                              hipStream_t stream) {
    const float* x = (const float*)d_in[0];
    const float* W1[3] = {(const float*)d_in[1], (const float*)d_in[7], (const float*)d_in[13]};
    const float* b1[3] = {(const float*)d_in[2], (const float*)d_in[8], (const float*)d_in[14]};
    const float* lg[3] = {(const float*)d_in[3], (const float*)d_in[9], (const float*)d_in[15]};
    const float* lb[3] = {(const float*)d_in[4], (const float*)d_in[10], (const float*)d_in[16]};
    const float* W2[3] = {(const float*)d_in[5], (const float*)d_in[11], (const float*)d_in[17]};
    const float* b2[3] = {(const float*)d_in[6], (const float*)d_in[12], (const float*)d_in[18]};

    char* ws = (char*)d_ws;
    size_t off = 0;
    u16* x_hi = (u16*)(ws + off); off += (size_t)BD * DD * 2;      // 134 MB
    u16* x_lo = (u16*)(ws + off); off += (size_t)BD * DD * 2;      // 134 MB
    u16* w_hi[3];
    u16* w_lo[3];
    for (int i = 0; i < 3; ++i) { w_hi[i] = (u16*)(ws + off); off += (size_t)DD * DD * 2; }
    for (int i = 0; i < 3; ++i) { w_lo[i] = (u16*)(ws + off); off += (size_t)DD * DD * 2; }
    float* h = (float*)(ws + off); off += (size_t)IDX_CAP * DD * 4; // 270 MB
    int* route = (int*)(ws + off); off += (size_t)BD * 4;
    int* idx_all = (int*)(ws + off); off += (size_t)IDX_CAP * 4;
    int* u_idx = (int*)(ws + off); off += (size_t)UCAP * 4;
    int* ctrl = (int*)(ws + off); off += 64;

    // 0) zero control/index buffers (ws is poisoned each replay)
    zero_misc<<<(IDX_CAP + 255) / 256, 256, 0, stream>>>(idx_all, u_idx, ctrl);

    // 1) precision splits
    split_f32<<<(BD * DD / 4) / 256, 256, 0, stream>>>(x, x_hi, x_lo, BD * DD / 4);
    for (int i = 0; i < 3; ++i)
        split_f32<<<(DD * DD / 4) / 256, 256, 0, stream>>>(W1[i], w_hi[i], w_lo[i], DD * DD / 4);

    // 2) branch 1 in plain bf16; route + near-tie flags
    gemm_bt<0, 0, 0><<<dim3(DD / 128, BD / 128), 256, 0, stream>>>(
        x_hi, nullptr, w_hi[0], nullptr, nullptr, h, nullptr, nullptr);
    ln_route<<<BD / 4, 256, 0, stream>>>(h, b1[0], lg[0], lb[0], W2[0], b2[0],
                                         route, ctrl, u_idx);

    // 3) split-precision recheck of flagged rows (gathered via u_idx; early-exit grid)
    gemm_bt<1, 1, 0><<<dim3(DD / 128, UCAP / 128), 256, 0, stream>>>(
        x_hi, x_lo, w_hi[0], w_lo[0], nullptr, h, u_idx, ctrl);
    ln_fixup<<<UCAP / 4, 256, 0, stream>>>(h, b1[0], lg[0], lb[0], W2[0], b2[0],
                                           route, ctrl, u_idx);

    // 4) compact rows into fake|real segments (128-padded boundary)
    init_ctrl<<<1, 1, 0, stream>>>(ctrl);
    compact<<<BD / 256, 256, 0, stream>>>(route, ctrl, idx_all);

    // 5) one combined gathered GEMM over both segments (per-row-block B select)
    gemm_bt<0, 1, 1><<<dim3(DD / 128, BD / 128 + 1), 256, 0, stream>>>(
        x_hi, nullptr, w_hi[1], nullptr, w_hi[2], h, idx_all, ctrl);

    // 6) final LN+head, scatter to out by original row
    ln_final<<<(BD + 128) / 4, 256, 0, stream>>>(
        h, b1[1], lg[1], lb[1], W2[1], b2[1],
        b1[2], lg[2], lb[2], W2[2], b2[2],
        ctrl, idx_all, (float*)d_out);
}

// Round 4
// 1631.618 us; speedup vs baseline: 1.4294x; 1.2354x over previous
//
#include <hip/hip_runtime.h>

#define BD 32768
#define DD 2048
#define LN_EPS 1e-5f
#define MARGIN 0.03f
#define UCAP 8192          // max rows re-checked at split precision (expected ~2k)
#define IDX_CAP 33024      // 32768 + 2*128 padding

typedef unsigned short u16;
typedef unsigned int u32;
typedef __bf16 bf16x8 __attribute__((ext_vector_type(8)));
typedef float floatx4 __attribute__((ext_vector_type(4)));

// ctrl layout: [0]=nf (count route==0), [1]=u_cnt, [2]=nf snapshot, [3]=nf_pad,
//              [4]=cursor_fake, [5]=cursor_real
__device__ inline u16 f2bf(float f) {
    u32 u = __builtin_bit_cast(u32, f);
    u32 r = (u + 0x7fffu + ((u >> 16) & 1u)) >> 16;
    return (u16)r;
}
__device__ inline float bf2f(u16 h) {
    return __builtin_bit_cast(float, ((u32)h) << 16);
}
__device__ inline void bf2x2(u32 p, float& lo, float& hi) {
    lo = __builtin_bit_cast(float, p << 16);
    hi = __builtin_bit_cast(float, p & 0xffff0000u);
}

__device__ inline void lds16(const void* g, void* l) {
    __builtin_amdgcn_global_load_lds(
        (const __attribute__((address_space(1))) u32*)g,
        (__attribute__((address_space(3))) u32*)l, 16, 0, 0);
}

__global__ __launch_bounds__(256) void zero_misc(int* idx_all, int* u_idx, int* ctrl) {
    int t = blockIdx.x * 256 + threadIdx.x;
    if (t < IDX_CAP) idx_all[t] = 0;
    if (t < UCAP) u_idx[t] = 0;
    if (t < 8) ctrl[t] = 0;
}

// fp32 -> (hi, lo) bf16 split, 4 elements/thread
__global__ __launch_bounds__(256) void split_f32(const float* __restrict__ in,
                                                 u16* __restrict__ hi,
                                                 u16* __restrict__ lo, int n4) {
    int i = blockIdx.x * 256 + threadIdx.x;
    if (i >= n4) return;
    float4 f = ((const float4*)in)[i];
    u16 h0 = f2bf(f.x), h1 = f2bf(f.y), h2 = f2bf(f.z), h3 = f2bf(f.w);
    u16 l0 = f2bf(f.x - bf2f(h0)), l1 = f2bf(f.y - bf2f(h1));
    u16 l2 = f2bf(f.z - bf2f(h2)), l3 = f2bf(f.w - bf2f(h3));
    ((ushort4*)hi)[i] = make_ushort4(h0, h1, h2, h3);
    ((ushort4*)lo)[i] = make_ushort4(l0, l1, l2, l3);
}

// ---------------------------------------------------------------------------
// Plain bf16 GEMM, BK=64, bf16 output. C[m][n] = sum_k A[m][k]*B[n][k].
// 128x128 tile. LDS 32 KB (A 16 KB + B 16 KB), 8 16B-quads per row,
// XOR-swizzled: slot s of row r holds global quad s ^ (r&7) -> every 8-lane
// phase of a fragment ds_read_b128 hits all 8 bank groups (conflict-free),
// and each A row consumes a full 128 B line per k-iter (kills the 4x
// over-fetch seen at BK=32).
// IDX: A rows gathered via ridx. DUAL: B selected per row-block segment.
template <int IDX, int DUAL>
__global__ __launch_bounds__(256) void gemm_plain(const u16* __restrict__ A,
                                                  const u16* __restrict__ B1,
                                                  const u16* __restrict__ B2,
                                                  u16* __restrict__ C,
                                                  const int* __restrict__ ridx,
                                                  const int* __restrict__ ctrl) {
    const int tid = threadIdx.x;
    const size_t bm = (size_t)blockIdx.y * 128;
    const size_t bn = (size_t)blockIdx.x * 128;

    const u16* Bp = B1;
    if (DUAL) {
        int nf_pad = ctrl[3];
        int limit = nf_pad + (BD - ctrl[2]);       // nf_pad + nr
        if ((int)bm >= limit) return;
        if ((int)bm >= nf_pad) Bp = B2;
    }

    __shared__ alignas(16) u16 smem[16384];        // A: [0,8192), B: [8192,16384)
    const int lane = tid & 63;
    const int wave = tid >> 6;
    const int wm = (wave >> 1) * 64, wn = (wave & 1) * 64;
    const int m16 = lane & 15, q = lane >> 4;

    // staging geometry: 4 quads per thread per matrix per iter
    int aRow[4], kq[4];
    size_t bOff[4];
#pragma unroll
    for (int s = 0; s < 4; ++s) {
        int e = s * 256 + tid;                     // 0..1023
        int row = e >> 3;
        int c = e & 7;
        kq[s] = (c ^ (row & 7)) * 8;               // staging-side swizzle
        aRow[s] = IDX ? ridx[bm + row] : (int)(bm + row);
        bOff[s] = (size_t)(bn + row) * DD;
    }
    // fragment-read swizzle slots for the two 32-wide k-slabs
    const int slot0 = ((q) ^ (m16 & 7)) * 8;
    const int slot1 = ((4 + q) ^ (m16 & 7)) * 8;

    floatx4 acc[4][4] = {};

    for (int k0 = 0; k0 < DD; k0 += 64) {
#pragma unroll
        for (int s = 0; s < 4; ++s) {
            int e = s * 256 + tid;
            lds16(A + (size_t)aRow[s] * DD + k0 + kq[s], &smem[e * 8]);
            lds16(Bp + bOff[s] + k0 + kq[s], &smem[8192 + e * 8]);
        }
        __syncthreads();

#pragma unroll
        for (int kk = 0; kk < 2; ++kk) {
            const int sl = kk ? slot1 : slot0;
            bf16x8 ah[4], bh[4];
#pragma unroll
            for (int i = 0; i < 4; ++i) {
                ah[i] = *(const bf16x8*)&smem[(wm + i * 16 + m16) * 64 + sl];
                bh[i] = *(const bf16x8*)&smem[8192 + (wn + i * 16 + m16) * 64 + sl];
            }
#pragma unroll
            for (int i = 0; i < 4; ++i)
#pragma unroll
                for (int j = 0; j < 4; ++j)
                    acc[i][j] = __builtin_amdgcn_mfma_f32_16x16x32_bf16(ah[i], bh[j], acc[i][j], 0, 0, 0);
        }
        __syncthreads();
    }

    // C/D layout (m89-verified): col = lane&15, row = (lane>>4)*4 + reg
#pragma unroll
    for (int i = 0; i < 4; ++i) {
#pragma unroll
        for (int r = 0; r < 4; ++r) {
            size_t grow = bm + wm + i * 16 + q * 4 + r;
            u16* crow = C + grow * DD + bn + wn + m16;
#pragma unroll
            for (int j = 0; j < 4; ++j) crow[j * 16] = f2bf(acc[i][j][r]);
        }
    }
}

// ---------------------------------------------------------------------------
// Split-precision GEMM (3-chain hi*hi+hi*lo+lo*hi), BK=32, fp32 out,
// A rows gathered via ridx, row-blocks beyond u_cnt exit. (Round-3 kernel.)
__global__ __launch_bounds__(256) void gemm_split(const u16* __restrict__ Ahi,
                                                  const u16* __restrict__ Alo,
                                                  const u16* __restrict__ Bhi,
                                                  const u16* __restrict__ Blo,
                                                  float* __restrict__ C,
                                                  const int* __restrict__ ridx,
                                                  const int* __restrict__ ctrl) {
    const int tid = threadIdx.x;
    const size_t bm = (size_t)blockIdx.y * 128;
    const size_t bn = (size_t)blockIdx.x * 128;

    int u = ctrl[1]; if (u > UCAP) u = UCAP;
    if ((int)bm >= u) return;

    __shared__ alignas(16) u16 smem[4 * 4096];
    const int lane = tid & 63;
    const int wave = tid >> 6;
    const int wm = (wave >> 1) * 64, wn = (wave & 1) * 64;
    const int m16 = lane & 15, q = lane >> 4;
    const int swz = (q ^ ((m16 >> 1) & 3)) * 8;

    int aRow[2], kq[2];
    size_t bOff[2];
#pragma unroll
    for (int s = 0; s < 2; ++s) {
        int e = s * 256 + tid;
        int row = e >> 2;
        int c = e & 3;
        kq[s] = (c ^ ((row >> 1) & 3)) * 8;
        aRow[s] = ridx[bm + row];
        bOff[s] = (size_t)(bn + row) * DD;
    }

    floatx4 acc[4][4] = {};

    for (int k0 = 0; k0 < DD; k0 += 32) {
#pragma unroll
        for (int s = 0; s < 2; ++s) {
            int e = s * 256 + tid;
            size_t aoff = (size_t)aRow[s] * DD + k0 + kq[s];
            size_t boff = bOff[s] + k0 + kq[s];
            lds16(Ahi + aoff, &smem[e * 8]);
            lds16(Bhi + boff, &smem[4096 + e * 8]);
            lds16(Alo + aoff, &smem[8192 + e * 8]);
            lds16(Blo + boff, &smem[12288 + e * 8]);
        }
        __syncthreads();

        bf16x8 ah[4], bh[4], al[4], bl[4];
#pragma unroll
        for (int i = 0; i < 4; ++i) {
            ah[i] = *(const bf16x8*)&smem[(wm + i * 16 + m16) * 32 + swz];
            bh[i] = *(const bf16x8*)&smem[4096 + (wn + i * 16 + m16) * 32 + swz];
            al[i] = *(const bf16x8*)&smem[8192 + (wm + i * 16 + m16) * 32 + swz];
            bl[i] = *(const bf16x8*)&smem[12288 + (wn + i * 16 + m16) * 32 + swz];
        }
#pragma unroll
        for (int i = 0; i < 4; ++i)
#pragma unroll
            for (int j = 0; j < 4; ++j) {
                acc[i][j] = __builtin_amdgcn_mfma_f32_16x16x32_bf16(ah[i], bh[j], acc[i][j], 0, 0, 0);
                acc[i][j] = __builtin_amdgcn_mfma_f32_16x16x32_bf16(ah[i], bl[j], acc[i][j], 0, 0, 0);
                acc[i][j] = __builtin_amdgcn_mfma_f32_16x16x32_bf16(al[i], bh[j], acc[i][j], 0, 0, 0);
            }
        __syncthreads();
    }

#pragma unroll
    for (int i = 0; i < 4; ++i)
#pragma unroll
        for (int r = 0; r < 4; ++r) {
            size_t grow = bm + wm + i * 16 + q * 4 + r;
            float* crow = C + grow * DD + bn + wn + m16;
#pragma unroll
            for (int j = 0; j < 4; ++j) crow[j * 16] = acc[i][j][r];
        }
}

// ---------------------------------------------------------------------------
// bf16-h LN core: +b1, LayerNorm, ReLU, W2 dot + b2. All lanes get l0,l1.
__device__ inline void ln_core16(const u16* __restrict__ hr,
                                 const float* __restrict__ b1,
                                 const float* __restrict__ g,
                                 const float* __restrict__ be,
                                 const float* __restrict__ W2,
                                 const float* __restrict__ b2,
                                 int lane, float& L0, float& L1) {
    float v[32];
    float sum = 0.f, sumsq = 0.f;
#pragma unroll
    for (int i = 0; i < 4; ++i) {
        int col = i * 512 + lane * 8;
        uint4 hv = *(const uint4*)(hr + col);
        float4 b0 = *(const float4*)(b1 + col);
        float4 b4 = *(const float4*)(b1 + col + 4);
        float f0, f1, f2, f3, f4, f5, f6, f7;
        bf2x2(hv.x, f0, f1); bf2x2(hv.y, f2, f3);
        bf2x2(hv.z, f4, f5); bf2x2(hv.w, f6, f7);
        f0 += b0.x; f1 += b0.y; f2 += b0.z; f3 += b0.w;
        f4 += b4.x; f5 += b4.y; f6 += b4.z; f7 += b4.w;
        v[i * 8 + 0] = f0; v[i * 8 + 1] = f1; v[i * 8 + 2] = f2; v[i * 8 + 3] = f3;
        v[i * 8 + 4] = f4; v[i * 8 + 5] = f5; v[i * 8 + 6] = f6; v[i * 8 + 7] = f7;
        sum += f0 + f1 + f2 + f3 + f4 + f5 + f6 + f7;
        sumsq += f0 * f0 + f1 * f1 + f2 * f2 + f3 * f3 + f4 * f4 + f5 * f5 + f6 * f6 + f7 * f7;
    }
#pragma unroll
    for (int off = 32; off > 0; off >>= 1) {
        sum += __shfl_xor(sum, off);
        sumsq += __shfl_xor(sumsq, off);
    }
    const float mu = sum * (1.f / 2048.f);
    const float var = sumsq * (1.f / 2048.f) - mu * mu;
    const float rstd = rsqrtf(var + LN_EPS);

    float l0 = 0.f, l1 = 0.f;
#pragma unroll
    for (int i = 0; i < 4; ++i) {
        int col = i * 512 + lane * 8;
#pragma unroll
        for (int hoff = 0; hoff < 8; hoff += 4) {
            float4 gg = *(const float4*)(g + col + hoff);
            float4 bbe = *(const float4*)(be + col + hoff);
            float4 w0 = *(const float4*)(W2 + col + hoff);
            float4 w1 = *(const float4*)(W2 + DD + col + hoff);
            float hn;
            hn = fmaxf((v[i * 8 + hoff + 0] - mu) * rstd * gg.x + bbe.x, 0.f); l0 += hn * w0.x; l1 += hn * w1.x;
            hn = fmaxf((v[i * 8 + hoff + 1] - mu) * rstd * gg.y + bbe.y, 0.f); l0 += hn * w0.y; l1 += hn * w1.y;
            hn = fmaxf((v[i * 8 + hoff + 2] - mu) * rstd * gg.z + bbe.z, 0.f); l0 += hn * w0.z; l1 += hn * w1.z;
            hn = fmaxf((v[i * 8 + hoff + 3] - mu) * rstd * gg.w + bbe.w, 0.f); l0 += hn * w0.w; l1 += hn * w1.w;
        }
    }
#pragma unroll
    for (int off = 32; off > 0; off >>= 1) {
        l0 += __shfl_xor(l0, off);
        l1 += __shfl_xor(l1, off);
    }
    L0 = l0 + b2[0];
    L1 = l1 + b2[1];
}

// fp32-h LN core (fixup path only)
__device__ inline void ln_core(const float* __restrict__ hr,
                               const float* __restrict__ b1,
                               const float* __restrict__ g,
                               const float* __restrict__ be,
                               const float* __restrict__ W2,
                               const float* __restrict__ b2,
                               int lane, float& L0, float& L1) {
    float v[32];
    float sum = 0.f, sumsq = 0.f;
#pragma unroll
    for (int i = 0; i < 8; ++i) {
        int col = i * 256 + lane * 4;
        float4 t = *(const float4*)(hr + col);
        float4 bb = *(const float4*)(b1 + col);
        t.x += bb.x; t.y += bb.y; t.z += bb.z; t.w += bb.w;
        v[i * 4 + 0] = t.x; v[i * 4 + 1] = t.y; v[i * 4 + 2] = t.z; v[i * 4 + 3] = t.w;
        sum += t.x + t.y + t.z + t.w;
        sumsq += t.x * t.x + t.y * t.y + t.z * t.z + t.w * t.w;
    }
#pragma unroll
    for (int off = 32; off > 0; off >>= 1) {
        sum += __shfl_xor(sum, off);
        sumsq += __shfl_xor(sumsq, off);
    }
    const float mu = sum * (1.f / 2048.f);
    const float var = sumsq * (1.f / 2048.f) - mu * mu;
    const float rstd = rsqrtf(var + LN_EPS);

    float l0 = 0.f, l1 = 0.f;
#pragma unroll
    for (int i = 0; i < 8; ++i) {
        int col = i * 256 + lane * 4;
        float4 gg = *(const float4*)(g + col);
        float4 bbe = *(const float4*)(be + col);
        float4 w0 = *(const float4*)(W2 + col);
        float4 w1 = *(const float4*)(W2 + DD + col);
        float hn;
        hn = fmaxf((v[i * 4 + 0] - mu) * rstd * gg.x + bbe.x, 0.f); l0 += hn * w0.x; l1 += hn * w1.x;
        hn = fmaxf((v[i * 4 + 1] - mu) * rstd * gg.y + bbe.y, 0.f); l0 += hn * w0.y; l1 += hn * w1.y;
        hn = fmaxf((v[i * 4 + 2] - mu) * rstd * gg.z + bbe.z, 0.f); l0 += hn * w0.z; l1 += hn * w1.z;
        hn = fmaxf((v[i * 4 + 3] - mu) * rstd * gg.w + bbe.w, 0.f); l0 += hn * w0.w; l1 += hn * w1.w;
    }
#pragma unroll
    for (int off = 32; off > 0; off >>= 1) {
        l0 += __shfl_xor(l0, off);
        l1 += __shfl_xor(l1, off);
    }
    L0 = l0 + b2[0];
    L1 = l1 + b2[1];
}

// Branch-1: route = argmax, count nf, flag near-tie rows for recheck.
__global__ __launch_bounds__(256) void ln_route(const u16* __restrict__ h,
                                                const float* __restrict__ b1,
                                                const float* __restrict__ g,
                                                const float* __restrict__ be,
                                                const float* __restrict__ W2,
                                                const float* __restrict__ b2,
                                                int* __restrict__ route,
                                                int* __restrict__ ctrl,
                                                int* __restrict__ u_idx) {
    const int wave = threadIdx.x >> 6, lane = threadIdx.x & 63;
    const size_t row = (size_t)blockIdx.x * 4 + wave;
    float l0, l1;
    ln_core16(h + row * DD, b1, g, be, W2, b2, lane, l0, l1);
    if (lane == 0) {
        int rt = (l0 >= l1) ? 0 : 1;
        route[row] = rt;
        atomicAdd(&ctrl[0], rt == 0 ? 1 : 0);
        if (fabsf(l0 - l1) < MARGIN) {
            int p = atomicAdd(&ctrl[1], 1);
            if (p < UCAP) u_idx[p] = (int)row;
        }
    }
}

// Recheck flagged rows with split-precision h (fp32, gathered order).
__global__ __launch_bounds__(256) void ln_fixup(const float* __restrict__ h,
                                                const float* __restrict__ b1,
                                                const float* __restrict__ g,
                                                const float* __restrict__ be,
                                                const float* __restrict__ W2,
                                                const float* __restrict__ b2,
                                                int* __restrict__ route,
                                                int* __restrict__ ctrl,
                                                const int* __restrict__ u_idx) {
    const int wave = threadIdx.x >> 6, lane = threadIdx.x & 63;
    const int r = blockIdx.x * 4 + wave;
    int u = ctrl[1]; if (u > UCAP) u = UCAP;
    if (r >= u) return;
    const int orig = u_idx[r];
    float l0, l1;
    ln_core(h + (size_t)r * DD, b1, g, be, W2, b2, lane, l0, l1);
    if (lane == 0) {
        int rt = (l0 >= l1) ? 0 : 1;
        int old = route[orig];
        if (rt != old) {
            atomicAdd(&ctrl[0], rt == 0 ? 1 : -1);
            route[orig] = rt;
        }
    }
}

__global__ void init_ctrl(int* ctrl) {
    int nf = ctrl[0];
    ctrl[2] = nf;
    ctrl[3] = (nf + 127) & ~127;
    ctrl[4] = 0;
    ctrl[5] = ctrl[3];
}

// Compact rows: fake segment at [0,nf), real segment at [nf_pad, nf_pad+nr).
__global__ __launch_bounds__(256) void compact(const int* __restrict__ route,
                                               int* __restrict__ ctrl,
                                               int* __restrict__ idx_all) {
    const int row = blockIdx.x * 256 + threadIdx.x;
    const int lane = threadIdx.x & 63;
    const bool isf = (route[row] == 0);
    unsigned long long m = __ballot(isf);
    int nfw = __popcll(m);
    int baseF = 0, baseR = 0;
    if (lane == 0) {
        baseF = atomicAdd(&ctrl[4], nfw);
        baseR = atomicAdd(&ctrl[5], 64 - nfw);
    }
    baseF = __shfl(baseF, 0);
    baseR = __shfl(baseR, 0);
    unsigned long long lt = (lane == 0) ? 0ull : ((~0ull) >> (64 - lane));
    int pre = __popcll(m & lt);
    int pos = isf ? (baseF + pre) : (baseR + (lane - pre));
    idx_all[pos] = row;
}

// Final pass over combined gathered bf16 h: per-segment params, scatter to out.
__global__ __launch_bounds__(256) void ln_final(const u16* __restrict__ h,
                                                const float* __restrict__ b1f, const float* __restrict__ gf,
                                                const float* __restrict__ bef, const float* __restrict__ W2f,
                                                const float* __restrict__ b2f,
                                                const float* __restrict__ b1r, const float* __restrict__ gr,
                                                const float* __restrict__ ber, const float* __restrict__ W2r,
                                                const float* __restrict__ b2r,
                                                const int* __restrict__ ctrl,
                                                const int* __restrict__ idx_all,
                                                float* __restrict__ out) {
    const int wave = threadIdx.x >> 6, lane = threadIdx.x & 63;
    const int r = blockIdx.x * 4 + wave;
    const int nf = ctrl[2], nf_pad = ctrl[3];
    const int nr = BD - nf;
    bool fake;
    if (r < nf) fake = true;
    else if (r >= nf_pad && r < nf_pad + nr) fake = false;
    else return;
    const int orig = idx_all[r];
    float l0, l1;
    ln_core16(h + (size_t)r * DD,
              fake ? b1f : b1r, fake ? gf : gr, fake ? bef : ber,
              fake ? W2f : W2r, fake ? b2f : b2r, lane, l0, l1);
    if (lane == 0) {
        out[(size_t)orig * 2 + 0] = l0;
        out[(size_t)orig * 2 + 1] = l1;
    }
}

extern "C" void kernel_launch(void* const* d_in, const int* in_sizes, int n_in,
                              void* d_out, int out_size, void* d_ws, size_t ws_size,
                              hipStream_t stream) {
    const float* x = (const float*)d_in[0];
    const float* W1[3] = {(const float*)d_in[1], (const float*)d_in[7], (const float*)d_in[13]};
    const float* b1[3] = {(const float*)d_in[2], (const float*)d_in[8], (const float*)d_in[14]};
    const float* lg[3] = {(const float*)d_in[3], (const float*)d_in[9], (const float*)d_in[15]};
    const float* lb[3] = {(const float*)d_in[4], (const float*)d_in[10], (const float*)d_in[16]};
    const float* W2[3] = {(const float*)d_in[5], (const float*)d_in[11], (const float*)d_in[17]};
    const float* b2[3] = {(const float*)d_in[6], (const float*)d_in[12], (const float*)d_in[18]};

    char* ws = (char*)d_ws;
    size_t off = 0;
    u16* x_hi = (u16*)(ws + off); off += (size_t)BD * DD * 2;       // 134 MB
    u16* x_lo = (u16*)(ws + off); off += (size_t)BD * DD * 2;       // 134 MB
    u16* w_hi[3];
    u16* w_lo[3];
    for (int i = 0; i < 3; ++i) { w_hi[i] = (u16*)(ws + off); off += (size_t)DD * DD * 2; }
    for (int i = 0; i < 3; ++i) { w_lo[i] = (u16*)(ws + off); off += (size_t)DD * DD * 2; }
    u16* h16 = (u16*)(ws + off); off += (size_t)IDX_CAP * DD * 2;   // 135 MB
    float* hfix = (float*)(ws + off); off += (size_t)UCAP * DD * 4; // 67 MB
    int* route = (int*)(ws + off); off += (size_t)BD * 4;
    int* idx_all = (int*)(ws + off); off += (size_t)IDX_CAP * 4;
    int* u_idx = (int*)(ws + off); off += (size_t)UCAP * 4;
    int* ctrl = (int*)(ws + off); off += 64;

    // 0) zero control/index buffers (ws is poisoned each replay)
    zero_misc<<<(IDX_CAP + 255) / 256, 256, 0, stream>>>(idx_all, u_idx, ctrl);

    // 1) precision splits
    split_f32<<<(BD * DD / 4) / 256, 256, 0, stream>>>(x, x_hi, x_lo, BD * DD / 4);
    for (int i = 0; i < 3; ++i)
        split_f32<<<(DD * DD / 4) / 256, 256, 0, stream>>>(W1[i], w_hi[i], w_lo[i], DD * DD / 4);

    // 2) branch 1 in plain bf16 (BK=64, bf16 h); route + near-tie flags
    gemm_plain<0, 0><<<dim3(DD / 128, BD / 128), 256, 0, stream>>>(
        x_hi, w_hi[0], nullptr, h16, nullptr, nullptr);
    ln_route<<<BD / 4, 256, 0, stream>>>(h16, b1[0], lg[0], lb[0], W2[0], b2[0],
                                         route, ctrl, u_idx);

    // 3) split-precision recheck of flagged rows (gathered; early-exit grid)
    gemm_split<<<dim3(DD / 128, UCAP / 128), 256, 0, stream>>>(
        x_hi, x_lo, w_hi[0], w_lo[0], hfix, u_idx, ctrl);
    ln_fixup<<<UCAP / 4, 256, 0, stream>>>(hfix, b1[0], lg[0], lb[0], W2[0], b2[0],
                                           route, ctrl, u_idx);

    // 4) compact rows into fake|real segments (128-padded boundary)
    init_ctrl<<<1, 1, 0, stream>>>(ctrl);
    compact<<<BD / 256, 256, 0, stream>>>(route, ctrl, idx_all);

    // 5) one combined gathered GEMM over both segments (per-row-block B select)
    gemm_plain<1, 1><<<dim3(DD / 128, BD / 128 + 1), 256, 0, stream>>>(
        x_hi, w_hi[1], w_hi[2], h16, idx_all, ctrl);

    // 6) final LN+head, scatter to out by original row
    ln_final<<<(BD + 128) / 4, 256, 0, stream>>>(
        h16, b1[1], lg[1], lb[1], W2[1], b2[1],
        b1[2], lg[2], lb[2], W2[2], b2[2],
        ctrl, idx_all, (float*)d_out);
}